// Round 9
// baseline (37.420 us; speedup 1.0000x reference)
//
#include <hip/hip_runtime.h>
#include <hip/hip_bf16.h>
#include <math.h>

// Problem constants
#define B_TOT 256
#define P_P   1152
#define J_J   160        // L*O
#define K_K   9216       // N_N * P_P
#define L_L   10

// Split-K: slice sg owns k-subset {n*1152 + p : p in [64*sg, 64*sg+64), all n}
// Block-local k order: kk = dp*8 + n  (dp = p - 64*sg)
#define SG 18
#define JG 5
#define MAGIC 0x5EEDF00Du

typedef __attribute__((ext_vector_type(8))) short short8;   // 8 x bf16
typedef __attribute__((ext_vector_type(4))) float f32x4;

__device__ __forceinline__ short f2bf(float f) {
    __hip_bfloat16 h = __float2bfloat16(f);   // native v_cvt (RNE) on gfx950
    return __builtin_bit_cast(short, h);
}

// ---------------------------------------------------------------------------
// SINGLE-DISPATCH fused kernel: split-K MFMA GEMM + flag-based fan-in +
// squash. grid = (8 bt, 18 sg, 5 jg), 256 threads = 4 waves.
//
// Coherence design (NO __threadfence, NO wbl2 — round 4's killer):
//  * part[] stores: relaxed agent-scope atomic stores (write-through to the
//    chip coherence point; per-instruction cache bits only).
//  * per-wave s_waitcnt vmcnt(0), barrier, then relaxed atomic EXCHANGE of
//    this block's flag in each of its 4 b-groups (8 batches per group).
//  * every block scans its 4 groups' 90 flags with relaxed atomic loads;
//    a block seeing all-90 == MAGIC finishes that group (>=1 finisher per
//    group guaranteed: the temporally-last swapper's scan follows its swap;
//    multiple finishers write identical bits -> deterministic).
//  * finisher: one ACQUIRE load (buffer_inv) then regular vectorized reads
//    of part, reduce over SG, squash, store out, reset flags to 0 for the
//    next graph replay (write-through; flushed at kernel end).
// Poison-safe: flags==0xAA.. or 0 != MAGIC; part fully overwritten first.
// ---------------------------------------------------------------------------
__global__ __launch_bounds__(256, 4) void gemm_fused(const float* __restrict__ x,
                                                     const float* __restrict__ W,
                                                     float* __restrict__ part,
                                                     unsigned* __restrict__ flags,
                                                     float* __restrict__ out) {
    const int bt = blockIdx.x;      // 0..7
    const int sg = blockIdx.y;      // 0..17
    const int jg = blockIdx.z;      // 0..4
    const int tid  = threadIdx.x;
    const int w    = tid >> 6;      // wave 0..3
    const int lane = tid & 63;
    const int b0 = bt * 32;
    const int p0 = sg * 64;
    const int j0 = jg * 32;

    __shared__ __align__(16) short As[32][520];   // staged x (33.3 KB)
    float (*redux)[64][17] = (float (*)[64][17])(&As[0][0]);  // union
    __shared__ int nall[4];

    // ---- stage x-tile: lane = dp; coalesced dword loads, cvt, b128 write ----
    #pragma unroll
    for (int i = 0; i < 8; ++i) {
        const int bb = w * 8 + i;
        const float* xr = x + (size_t)(b0 + bb) * K_K + p0 + lane;
        short8 sh;
        #pragma unroll
        for (int n = 0; n < 8; ++n)
            sh[n] = f2bf(xr[(size_t)n * P_P]);
        *reinterpret_cast<short8*>(&As[bb][lane * 8]) = sh;  // kk = lane*8 + n
    }
    __syncthreads();

    const int m  = lane & 15;
    const int kq = lane >> 4;       // 0..3

    f32x4 acc00 = {0.f,0.f,0.f,0.f}, acc01 = {0.f,0.f,0.f,0.f};
    f32x4 acc10 = {0.f,0.f,0.f,0.f}, acc11 = {0.f,0.f,0.f,0.f};

    // B: p = p0 + w*16 + ks*4 + kq, j = j0 + m (+16 for j-chain 1)
    const float* wbase = W + (size_t)(p0 + w * 16 + kq) * 1280 + (size_t)(j0 + m) * 8;

    #pragma unroll
    for (int ks = 0; ks < 4; ++ks) {
        const short8 af0 =
            *reinterpret_cast<const short8*>(&As[m][w * 128 + ks * 32 + kq * 8]);
        const short8 af1 =
            *reinterpret_cast<const short8*>(&As[m + 16][w * 128 + ks * 32 + kq * 8]);
        const float* wp = wbase + (size_t)ks * 4 * 1280;
        const f32x4 a0 = *reinterpret_cast<const f32x4*>(wp);
        const f32x4 a1 = *reinterpret_cast<const f32x4*>(wp + 4);
        const f32x4 c0 = *reinterpret_cast<const f32x4*>(wp + 128);
        const f32x4 c1 = *reinterpret_cast<const f32x4*>(wp + 132);
        short8 bf0, bf1;
        #pragma unroll
        for (int e = 0; e < 4; ++e) {
            bf0[e]     = f2bf(a0[e]);
            bf0[e + 4] = f2bf(a1[e]);
            bf1[e]     = f2bf(c0[e]);
            bf1[e + 4] = f2bf(c1[e]);
        }
        acc00 = __builtin_amdgcn_mfma_f32_16x16x32_bf16(af0, bf0, acc00, 0, 0, 0);
        acc01 = __builtin_amdgcn_mfma_f32_16x16x32_bf16(af0, bf1, acc01, 0, 0, 0);
        acc10 = __builtin_amdgcn_mfma_f32_16x16x32_bf16(af1, bf0, acc10, 0, 0, 0);
        acc11 = __builtin_amdgcn_mfma_f32_16x16x32_bf16(af1, bf1, acc11, 0, 0, 0);
    }

    __syncthreads();   // all As reads done -> safe to reuse LDS as redux

    // ---- cross-wave split-K reduce (deterministic order w = 0..3) ----
    #pragma unroll
    for (int r = 0; r < 4; ++r) {
        redux[w][lane][r]      = acc00[r];
        redux[w][lane][r + 4]  = acc01[r];
        redux[w][lane][r + 8]  = acc10[r];
        redux[w][lane][r + 12] = acc11[r];
    }
    __syncthreads();

    // ---- part stores: write-through (relaxed agent atomics) ----
    {
        const int bl = tid >> 3;        // local b 0..31
        const int q  = tid & 7;         // j-quad 0..7
        const int ji = q >> 2;
        const int mq = q & 3;
        const int bi  = bl >> 4;
        const int kqd = (bl >> 2) & 3;
        const int r   = bl & 3;
        const int c   = bi * 8 + ji * 4 + r;
        float* dst = &part[((size_t)(b0 + bl) * SG + sg) * J_J + j0 + q * 4];
        #pragma unroll
        for (int u = 0; u < 4; ++u) {
            const int ln = kqd * 16 + mq * 4 + u;
            const float s = redux[0][ln][c] + redux[1][ln][c]
                          + redux[2][ln][c] + redux[3][ln][c];
            __hip_atomic_store(dst + u, s, __ATOMIC_RELAXED,
                               __HIP_MEMORY_SCOPE_AGENT);
        }
    }
    asm volatile("s_waitcnt vmcnt(0)" ::: "memory");  // each wave's stores done
    __syncthreads();                                  // all waves' stores done

    // ---- publish: set this block's flag in each of its 4 b-groups ----
    if (tid < 4)
        (void)__hip_atomic_exchange(&flags[(bt * 4 + tid) * 90 + sg * 5 + jg],
                                    MAGIC, __ATOMIC_RELAXED,
                                    __HIP_MEMORY_SCOPE_AGENT);
    asm volatile("s_waitcnt vmcnt(0)" ::: "memory");
    __syncthreads();

    // ---- scan: is any of our 4 groups fully published? ----
    if (tid < 4) nall[tid] = 0;
    __syncthreads();
    #pragma unroll
    for (int gi = 0; gi < 4; ++gi) {
        if (tid < 90) {
            const unsigned v = __hip_atomic_load(
                &flags[(bt * 4 + gi) * 90 + tid], __ATOMIC_RELAXED,
                __HIP_MEMORY_SCOPE_AGENT);
            if (v != MAGIC) nall[gi] = 1;   // benign race
        }
    }
    __syncthreads();
    if (nall[0] & nall[1] & nall[2] & nall[3]) return;   // not a finisher

    // ---- acquire: invalidate local caches so part reads see LLC truth ----
    if (tid == 0)
        (void)__hip_atomic_load(&flags[bt * 4 * 90], __ATOMIC_ACQUIRE,
                                __HIP_MEMORY_SCOPE_AGENT);
    __syncthreads();

    float (*sld)[J_J] = (float (*)[J_J])(&As[0][0]);          // 8 x 160
    float* scl = (float*)(&As[0][0]) + 8 * J_J;               // 8 x 16
    const f32x4* part4 = reinterpret_cast<const f32x4*>(part);
    f32x4* out4 = reinterpret_cast<f32x4*>(out);

    for (int gi = 0; gi < 4; ++gi) {
        if (nall[gi]) continue;              // block-uniform
        const int gb = b0 + gi * 8;          // 8 batches this group
        __syncthreads();                     // LDS reuse boundary
        // reduce over SG (fixed order -> deterministic bits)
        for (int u = tid; u < 320; u += 256) {
            const int bb = u / 40, quad = u - (u / 40) * 40;
            f32x4 s = {0.f, 0.f, 0.f, 0.f};
            #pragma unroll
            for (int si = 0; si < SG; ++si)
                s += part4[((size_t)(gb + bb) * SG + si) * 40 + quad];
            *reinterpret_cast<f32x4*>(&sld[bb][quad * 4]) = s;
        }
        __syncthreads();
        if (tid < 128) {
            const int bb = tid >> 4, o = tid & 15;
            float ms = 0.f;
            #pragma unroll
            for (int l = 0; l < L_L; ++l) {
                const float v = sld[bb][l * 16 + o];
                ms = fmaf(v, v, ms);
            }
            scl[tid] = sqrtf(ms) / (1.0f + ms);
        }
        __syncthreads();
        for (int u = tid; u < 320; u += 256) {
            const int bb = u / 40, quad = u - (u / 40) * 40;
            const f32x4 s = *reinterpret_cast<const f32x4*>(&sld[bb][quad * 4]);
            f32x4 r;
            #pragma unroll
            for (int e = 0; e < 4; ++e)
                r[e] = s[e] * scl[bb * 16 + ((quad * 4 + e) & 15)];
            out4[(size_t)(gb + bb) * 40 + quad] = r;
        }
        __syncthreads();
        // reset flags for the next replay (write-through)
        if (tid < 90)
            __hip_atomic_store(&flags[(bt * 4 + gi) * 90 + tid], 0u,
                               __ATOMIC_RELAXED, __HIP_MEMORY_SCOPE_AGENT);
    }
}

// ---------------------------------------------------------------------------
extern "C" void kernel_launch(void* const* d_in, const int* in_sizes, int n_in,
                              void* d_out, int out_size, void* d_ws, size_t ws_size,
                              hipStream_t stream) {
    const float* x = (const float*)d_in[0];   // (256, 8, 1152)
    const float* W = (const float*)d_in[1];   // (1, 1152, 10, 16, 8)
    float* out = (float*)d_out;               // (256, 10, 16)

    float*    part  = (float*)d_ws;                         // [256][18][160] fp32
    unsigned* flags = (unsigned*)(part + (size_t)B_TOT * SG * J_J);  // [32][90]

    dim3 gg(B_TOT / 32, SG, JG);
    gemm_fused<<<gg, 256, 0, stream>>>(x, W, part, flags, out);
}

// Round 10
// 17.295 us; speedup vs baseline: 2.1636x; 2.1636x over previous
//
#include <hip/hip_runtime.h>
#include <hip/hip_bf16.h>
#include <math.h>

// Problem constants
#define B_TOT 256
#define P_P   1152
#define J_J   160        // L*O
#define K_K   9216       // N_N * P_P
#define L_L   10

// Split-K: slice sg owns k-subset {n*1152 + p : p in [64*sg, 64*sg+64), all n}
// Block-local k order: kk = dp*8 + n  (dp = p - 64*sg)
#define SG 18
#define JG 5

typedef __attribute__((ext_vector_type(8))) short short8;   // 8 x bf16
typedef __attribute__((ext_vector_type(4))) float f32x4;

__device__ __forceinline__ short f2bf(float f) {
    __hip_bfloat16 h = __float2bfloat16(f);   // native v_cvt (RNE) on gfx950
    return __builtin_bit_cast(short, h);
}

// ---------------------------------------------------------------------------
// Kernel 1: split-K MFMA GEMM reading x and W directly.
// grid = (8 bt, 18 sg, 5 jg), 256 threads = 4 waves, 4 blocks/CU.
// KEY CHANGE vs R8: the 16 W dwordx4 loads are ISSUED FIRST (they don't
// depend on LDS), so their L2/L3 latency overlaps the x-stage HBM latency
// instead of serializing after the barrier (compiler can't hoist loads
// above __syncthreads). Only bv is held in regs (64 VGPR) — R7 showed
// hoisting xv too spills past the 128 cap.
// Block tile: 32 b x 32 j x 512 k; wave w owns kk in [w*128, w*128+128).
// ---------------------------------------------------------------------------
__global__ __launch_bounds__(256, 4) void gemm_direct(const float* __restrict__ x,
                                                      const float* __restrict__ W,
                                                      float* __restrict__ part) {
    const int bt = blockIdx.x;      // 0..7
    const int sg = blockIdx.y;      // 0..17
    const int jg = blockIdx.z;      // 0..4
    const int tid  = threadIdx.x;
    const int w    = tid >> 6;      // wave 0..3
    const int lane = tid & 63;
    const int b0 = bt * 32;
    const int p0 = sg * 64;
    const int j0 = jg * 32;
    const int m  = lane & 15;
    const int kq = lane >> 4;       // 0..3

    __shared__ __align__(16) short As[32][520];   // rows padded; 2-way alias only
    float (*redux)[64][17] = (float (*)[64][17])(&As[0][0]);  // union (17.4 KB)

    // ---- phase 0: issue ALL 16 W loads up front (latency overlaps staging) ----
    // B: p = p0 + w*16 + ks*4 + kq, j = j0 + m (+16 for j-chain 1)
    const float* wbase = W + (size_t)(p0 + w * 16 + kq) * 1280 + (size_t)(j0 + m) * 8;
    f32x4 bva[4], bvb[4], bvc[4], bvd[4];
    #pragma unroll
    for (int ks = 0; ks < 4; ++ks) {
        const float* wp = wbase + (size_t)ks * 4 * 1280;
        bva[ks] = *reinterpret_cast<const f32x4*>(wp);
        bvb[ks] = *reinterpret_cast<const f32x4*>(wp + 4);
        bvc[ks] = *reinterpret_cast<const f32x4*>(wp + 128);
        bvd[ks] = *reinterpret_cast<const f32x4*>(wp + 132);
    }

    // ---- phase 1: stage x-tile; lane = dp, coalesced dword loads ----
    #pragma unroll
    for (int i = 0; i < 8; ++i) {
        const int bb = w * 8 + i;
        const float* xr = x + (size_t)(b0 + bb) * K_K + p0 + lane;
        short8 sh;
        #pragma unroll
        for (int n = 0; n < 8; ++n)
            sh[n] = f2bf(xr[(size_t)n * P_P]);
        *reinterpret_cast<short8*>(&As[bb][lane * 8]) = sh;  // kk = lane*8 + n
    }
    __syncthreads();

    // ---- phase 2: MFMA chain (all operands in reg/LDS now) ----
    f32x4 acc00 = {0.f,0.f,0.f,0.f}, acc01 = {0.f,0.f,0.f,0.f};
    f32x4 acc10 = {0.f,0.f,0.f,0.f}, acc11 = {0.f,0.f,0.f,0.f};

    #pragma unroll
    for (int ks = 0; ks < 4; ++ks) {
        const short8 af0 =
            *reinterpret_cast<const short8*>(&As[m][w * 128 + ks * 32 + kq * 8]);
        const short8 af1 =
            *reinterpret_cast<const short8*>(&As[m + 16][w * 128 + ks * 32 + kq * 8]);
        short8 bf0, bf1;
        #pragma unroll
        for (int e = 0; e < 4; ++e) {
            bf0[e]     = f2bf(bva[ks][e]);
            bf0[e + 4] = f2bf(bvb[ks][e]);
            bf1[e]     = f2bf(bvc[ks][e]);
            bf1[e + 4] = f2bf(bvd[ks][e]);
        }
        acc00 = __builtin_amdgcn_mfma_f32_16x16x32_bf16(af0, bf0, acc00, 0, 0, 0);
        acc01 = __builtin_amdgcn_mfma_f32_16x16x32_bf16(af0, bf1, acc01, 0, 0, 0);
        acc10 = __builtin_amdgcn_mfma_f32_16x16x32_bf16(af1, bf0, acc10, 0, 0, 0);
        acc11 = __builtin_amdgcn_mfma_f32_16x16x32_bf16(af1, bf1, acc11, 0, 0, 0);
    }

    __syncthreads();   // all As reads done -> safe to reuse LDS as redux

    // ---- cross-wave split-K reduce (deterministic order w = 0..3) ----
    #pragma unroll
    for (int r = 0; r < 4; ++r) {
        redux[w][lane][r]      = acc00[r];
        redux[w][lane][r + 4]  = acc01[r];
        redux[w][lane][r + 8]  = acc10[r];
        redux[w][lane][r + 12] = acc11[r];
    }
    __syncthreads();

    // ---- coalesced float4 partial stores: 256 thr x 4 floats = 1024 ----
    {
        const int bl = tid >> 3;        // local b 0..31
        const int q  = tid & 7;         // j-quad 0..7
        const int ji = q >> 2;          // j half
        const int mq = q & 3;           // m quad
        const int bi  = bl >> 4;        // b half
        const int kqd = (bl >> 2) & 3;  // D-row quarter
        const int r   = bl & 3;         // D reg
        const int c   = bi * 8 + ji * 4 + r;
        f32x4 v;
        #pragma unroll
        for (int u = 0; u < 4; ++u) {
            const int ln = kqd * 16 + mq * 4 + u;
            v[u] = redux[0][ln][c] + redux[1][ln][c]
                 + redux[2][ln][c] + redux[3][ln][c];
        }
        *reinterpret_cast<f32x4*>(
            &part[((size_t)(b0 + bl) * SG + sg) * J_J + j0 + q * 4]) = v;
    }
}

// ---------------------------------------------------------------------------
// Kernel 2: reduce partials over slices + squash -> out.
// grid 256 (one b each), 128 threads. float4 loads; 3 slice-thirds in
// parallel (threads 0..119), LDS fan-in, squash over the L axis.
// ---------------------------------------------------------------------------
__global__ __launch_bounds__(128) void reduce_squash(const float* __restrict__ part,
                                                     float* __restrict__ out) {
    const int b   = blockIdx.x;
    const int tid = threadIdx.x;
    __shared__ f32x4 psum[3][40];
    __shared__ float sld[J_J];
    __shared__ float scl[16];

    const f32x4* p4 = reinterpret_cast<const f32x4*>(part + (size_t)b * SG * J_J);
    const int jq  = tid % 40;
    const int sgt = tid / 40;       // 0..2 active (threads 120..127 idle)
    if (sgt < 3) {
        f32x4 s = {0.f, 0.f, 0.f, 0.f};
        #pragma unroll
        for (int si = 0; si < 6; ++si)
            s += p4[(sgt * 6 + si) * 40 + jq];
        psum[sgt][jq] = s;
    }
    __syncthreads();
    if (tid < 40) {
        const f32x4 t = psum[0][tid] + psum[1][tid] + psum[2][tid];
        *reinterpret_cast<f32x4*>(&sld[tid * 4]) = t;
    }
    __syncthreads();
    if (tid < 16) {
        float ms = 0.f;
        #pragma unroll
        for (int l = 0; l < L_L; ++l) {
            const float v = sld[l * 16 + tid];
            ms = fmaf(v, v, ms);
        }
        scl[tid] = sqrtf(ms) / (1.0f + ms);
    }
    __syncthreads();
    out[(size_t)b * J_J + tid] = sld[tid] * scl[tid & 15];
    if (tid < 32) {
        const int j = 128 + tid;
        out[(size_t)b * J_J + j] = sld[j] * scl[j & 15];
    }
}

// ---------------------------------------------------------------------------
extern "C" void kernel_launch(void* const* d_in, const int* in_sizes, int n_in,
                              void* d_out, int out_size, void* d_ws, size_t ws_size,
                              hipStream_t stream) {
    const float* x = (const float*)d_in[0];   // (256, 8, 1152)
    const float* W = (const float*)d_in[1];   // (1, 1152, 10, 16, 8)
    float* out = (float*)d_out;               // (256, 10, 16)

    float* part = (float*)d_ws;               // [256][18][160] fp32 = 2.95 MB

    dim3 gg(B_TOT / 32, SG, JG);
    gemm_direct<<<gg, 256, 0, stream>>>(x, W, part);

    reduce_squash<<<B_TOT, 128, 0, stream>>>(part, out);
}